// Round 13
// baseline (49.953 us; speedup 1.0000x reference)
//
#include <hip/hip_runtime.h>

typedef __attribute__((ext_vector_type(8))) _Float16 half8;
typedef __attribute__((ext_vector_type(4))) float f32x4;

// ---- constants from the reference ----
#define COS_M 0.98006657784124163f
#define SIN_M 0.19866933079506122f
#define TH_C  (-0.98006657784124163f)
#define MM_C  0.039733866159012244f
#define S_OVER_TEMP (10.0f / 0.07f)
#define LOG2E 1.44269504088896340736f
#define LN2   0.69314718055994530942f

// monotone-in-c transform: c -> S*phi(c)/TEMP (loss invariant to stabilizer
// choice, so xform(rowmax * invn) works as the log-sum-exp stabilizer)
__device__ inline float xform(float c) {
  float s2 = fmaxf(1.0f - c * c, 0.0f);
  float sn = sqrtf(s2);
  float phi = c * COS_M - sn * SIN_M;
  float out = (c - TH_C > 0.0f) ? phi : (c - MM_C);
  return out * S_OVER_TEMP;
}

// ---- K1: cf = l2norm rows of concat(views) -> f16 (R6-proven) --------------
__global__ __launch_bounds__(64) void k_normalize(const float* __restrict__ feats,
                                                  _Float16* __restrict__ cfn,
                                                  float* __restrict__ out) {
  const int i = blockIdx.x;  // row in [0, 2048)
  if (i == 0 && threadIdx.x == 0) out[0] = 0.0f;  // stream-ordered before K2
  const int b = i & 1023, v = i >> 10;
  const float* src = feats + ((size_t)b * 2 + v) * 192;
  const int t = threadIdx.x;
  float x0 = src[t], x1 = src[t + 64], x2 = src[t + 128];
  float ss = x0 * x0 + x1 * x1 + x2 * x2;
#pragma unroll
  for (int o = 32; o; o >>= 1) ss += __shfl_xor(ss, o);
  float inv = 1.0f / fmaxf(sqrtf(ss), 1e-12f);
  _Float16* dst = cfn + (size_t)i * 192;
  dst[t]       = (_Float16)(x0 * inv);
  dst[t + 64]  = (_Float16)(x1 * inv);
  dst[t + 128] = (_Float16)(x2 * inv);
}

// ---- K2: merged GEMM+loss. 128 blocks x 16 rows x 2048 cols, 16 waves. -----
// Per block: loop 8 col-tiles of 256 rows of cfn; stage tile in LDS with the
// R1-proven coalesced stride-200 pattern; wave w owns cols w*16+lr; C stays in
// registers (acc[8], f32); stats + exp straight from f32 acc (R12-validated
// math, fixed memory path). One atomicAdd per block (128 total).
__global__ __launch_bounds__(1024) void k_merged(const _Float16* __restrict__ cfn,
                                                 const int* __restrict__ labels,
                                                 float* __restrict__ out) {
  __shared__ alignas(16) _Float16 lb[256 * 200];  // 100 KB, stride 200 (proven)
  __shared__ float sstat[2][16][16];  // [ss|mx][row][wave]
  __shared__ float estat[3][16][16];  // [es|ps|cn][row][wave]
  __shared__ int labrow_s[16];
  __shared__ float lossr[16];

  const int t = threadIdx.x;
  const int w = t >> 6;  // wave 0..15: owns cols ct*256 + w*16 + lr
  const int lane = t & 63;
  const int lr = lane & 15, kg = lane >> 4;
  const int R = blockIdx.x * 16;  // this block's 16 rows

  if (t < 16) labrow_s[t] = labels[(R + t) & 1023];

  // A fragments: row R+lr, all K; loaded once, reused for all 8 tiles
  half8 af[6];
  {
    const _Float16* arow = cfn + (size_t)(R + lr) * 192;
#pragma unroll
    for (int kc = 0; kc < 6; ++kc) af[kc] = *(const half8*)&arow[kc * 32 + kg * 8];
  }

  const int rr = t >> 2, h = t & 3;  // staging: 4 threads/row, 48 f16 each
  f32x4 acc[8];

#pragma unroll
  for (int ct = 0; ct < 8; ++ct) {  // unrolled: acc[] indices compile-time
    {  // stage tile ct: 256 rows x 192 f16, coalesced, stride-200 LDS
      const _Float16* src = cfn + (size_t)(ct * 256 + rr) * 192 + h * 48;
      _Float16* dst = lb + rr * 200 + h * 48;
#pragma unroll
      for (int q = 0; q < 6; ++q)
        *(half8*)(dst + q * 8) = *(const half8*)(src + q * 8);
    }
    __syncthreads();
    half8 bf[6];
    const _Float16* brow = lb + (w * 16 + lr) * 200;
#pragma unroll
    for (int kc = 0; kc < 6; ++kc) bf[kc] = *(const half8*)&brow[kc * 32 + kg * 8];
    f32x4 a = (f32x4){0.f, 0.f, 0.f, 0.f};
#pragma unroll
    for (int kc = 0; kc < 6; ++kc)
      a = __builtin_amdgcn_mfma_f32_16x16x32_f16(af[kc], bf[kc], a, 0, 0, 0);
    acc[ct] = a;  // C: row = R + kg*4+e, col = ct*256 + w*16 + lr
    __syncthreads();  // LDS reuse barrier
  }

  // ---- row stats from f32 acc (pre-rounding; R12-validated) ----
  float ssv[4], mxv[4];
#pragma unroll
  for (int e = 0; e < 4; ++e) { ssv[e] = 0.f; mxv[e] = -3.4e38f; }
#pragma unroll
  for (int ct = 0; ct < 8; ++ct)
#pragma unroll
    for (int e = 0; e < 4; ++e) {
      const float c = acc[ct][e];
      ssv[e] += c * c;
      mxv[e] = fmaxf(mxv[e], c);
    }
#pragma unroll
  for (int o = 1; o < 16; o <<= 1)
#pragma unroll
    for (int e = 0; e < 4; ++e) {
      ssv[e] += __shfl_xor(ssv[e], o);
      mxv[e] = fmaxf(mxv[e], __shfl_xor(mxv[e], o));
    }
  if (lr == 0)
#pragma unroll
    for (int e = 0; e < 4; ++e) {
      sstat[0][kg * 4 + e][w] = ssv[e];
      sstat[1][kg * 4 + e][w] = mxv[e];
    }
  __syncthreads();

  float invn[4], Mst[4];
#pragma unroll
  for (int e = 0; e < 4; ++e) {
    float ss = 0.f, mx = -3.4e38f;
#pragma unroll
    for (int q = 0; q < 16; ++q) {
      ss += sstat[0][kg * 4 + e][q];
      mx = fmaxf(mx, sstat[1][kg * 4 + e][q]);
    }
    invn[e] = 1.0f / fmaxf(sqrtf(ss), 1e-12f);
    Mst[e] = xform(mx * invn[e]);  // stabilizer (loss-invariant choice)
  }

  // ---- exp pass straight from registers ----
  float es[4] = {0.f, 0.f, 0.f, 0.f}, ps[4] = {0.f, 0.f, 0.f, 0.f},
        cn[4] = {0.f, 0.f, 0.f, 0.f};
#pragma unroll
  for (int ct = 0; ct < 8; ++ct) {
    const int col = ct * 256 + w * 16 + lr;
    const int lcol = labels[col & 1023];  // 8KB table: L1-resident
#pragma unroll
    for (int e = 0; e < 4; ++e) {
      const int i = R + kg * 4 + e;
      const float lg = xform(acc[ct][e] * invn[e]) - Mst[e];
      if (col != i) {
        es[e] += exp2f(lg * LOG2E);
        if (lcol == labrow_s[kg * 4 + e]) { ps[e] += lg; cn[e] += 1.f; }
      }
    }
  }
#pragma unroll
  for (int o = 1; o < 16; o <<= 1)
#pragma unroll
    for (int e = 0; e < 4; ++e) {
      es[e] += __shfl_xor(es[e], o);
      ps[e] += __shfl_xor(ps[e], o);
      cn[e] += __shfl_xor(cn[e], o);
    }
  if (lr == 0)
#pragma unroll
    for (int e = 0; e < 4; ++e) {
      estat[0][kg * 4 + e][w] = es[e];
      estat[1][kg * 4 + e][w] = ps[e];
      estat[2][kg * 4 + e][w] = cn[e];
    }
  __syncthreads();

  // ---- finish: 256 threads, row = t>>4, wave-slot q = t&15 ----
  if (t < 256) {
    const int row = t >> 4, q = t & 15;
    float e_ = estat[0][row][q], p_ = estat[1][row][q], c_ = estat[2][row][q];
#pragma unroll
    for (int o = 1; o < 16; o <<= 1) {  // masks 1,2,4,8: stay in 16-group
      e_ += __shfl_xor(e_, o);
      p_ += __shfl_xor(p_, o);
      c_ += __shfl_xor(c_, o);
    }
    if (q == 0) lossr[row] = -(p_ / c_ - log2f(e_) * LN2);
  }
  __syncthreads();
  if (t == 0) {
    float s = 0.f;
#pragma unroll
    for (int r = 0; r < 16; ++r) s += lossr[r];
    atomicAdd(out, s * (1.0f / 2048.0f));  // 128 atomics total
  }
}

extern "C" void kernel_launch(void* const* d_in, const int* in_sizes, int n_in,
                              void* d_out, int out_size, void* d_ws, size_t ws_size,
                              hipStream_t stream) {
  const float* feats = (const float*)d_in[0];
  const int* labels = (const int*)d_in[1];
  // d_in[2]/d_in[3] (fc_w/fc_b) are provably dead: atten == 1.0 exactly

  char* ws = (char*)d_ws;
  _Float16* cfn = (_Float16*)ws;  // 2048*192*2 = 768 KiB (L2/L3-resident)

  k_normalize<<<2048, 64, 0, stream>>>(feats, cfn, (float*)d_out);
  k_merged<<<128, 1024, 0, stream>>>(cfn, labels, (float*)d_out);
}

// Round 14
// 39.150 us; speedup vs baseline: 1.2759x; 1.2759x over previous
//
#include <hip/hip_runtime.h>

typedef __attribute__((ext_vector_type(8))) _Float16 half8;
typedef __attribute__((ext_vector_type(4))) float f32x4;

// ---- constants from the reference ----
#define COS_M 0.98006657784124163f
#define SIN_M 0.19866933079506122f
#define TH_C  (-0.98006657784124163f)
#define MM_C  0.039733866159012244f
#define S_OVER_TEMP (10.0f / 0.07f)
#define LOG2E 1.44269504088896340736f
#define LN2   0.69314718055994530942f

// monotone-in-c transform: c -> S*phi(c)/TEMP (loss invariant to stabilizer
// choice, so xform(rowmax * invn) works as the log-sum-exp stabilizer)
__device__ inline float xform(float c) {
  float s2 = fmaxf(1.0f - c * c, 0.0f);
  float sn = sqrtf(s2);
  float phi = c * COS_M - sn * SIN_M;
  float out = (c - TH_C > 0.0f) ? phi : (c - MM_C);
  return out * S_OVER_TEMP;
}

// ---- K1: l2norm rows -> f16 in FRAGMENT-MAJOR layout --------------------------
// cfnF[(row>>4)*3072 + kc*512 + kg*128 + (row&15)*8 + e] = cfn[row][kc*32+kg*8+e]
// so an mfma_16x16x32_f16 A/B fragment (lane: row/col=lane&15, k-chunk=lane>>4)
// is ONE coalesced 16B/lane load: 16 lanes cover 256B contiguous per kg.
__global__ __launch_bounds__(64) void k_normfrag(const float* __restrict__ feats,
                                                 _Float16* __restrict__ cfnF,
                                                 float* __restrict__ out) {
  const int i = blockIdx.x;  // row in [0, 2048)
  if (i == 0 && threadIdx.x == 0) out[0] = 0.0f;  // stream-ordered before k_fused
  const int b = i & 1023, v = i >> 10;
  const float* src = feats + ((size_t)b * 2 + v) * 192;
  const int t = threadIdx.x;
  float x[3] = {src[t], src[t + 64], src[t + 128]};
  float ss = x[0] * x[0] + x[1] * x[1] + x[2] * x[2];
#pragma unroll
  for (int o = 32; o; o >>= 1) ss += __shfl_xor(ss, o);
  const float inv = 1.0f / fmaxf(sqrtf(ss), 1e-12f);
  _Float16* gdst = cfnF + (size_t)(i >> 4) * 3072 + (i & 15) * 8;
#pragma unroll
  for (int p = 0; p < 3; ++p) {
    const int k = t + 64 * p;
    gdst[(k >> 5) * 512 + ((k >> 3) & 3) * 128 + (k & 7)] = (_Float16)(x[p] * inv);
  }
}

// ---- K2: fused GEMM+loss. 128 blocks x 16 rows x 2048 cols, 16 waves, NO LDS
// staging, NO barriers in the main loop. Wave w owns cols [w*128, w*128+128);
// A/B frags stream from cfnF coalesced; C (16x2048) lives in registers; stats
// and exp pass from f32 acc (R12/R13-validated math). 1 atomicAdd per block.
__global__ __launch_bounds__(1024) void k_fused(const _Float16* __restrict__ cfnF,
                                                const int* __restrict__ labels,
                                                float* __restrict__ out) {
  __shared__ float sstat[2][16][16];  // [ss|mx][row][wave]
  __shared__ float estat[3][16][16];  // [es|ps|cn][row][wave]
  __shared__ int labrow_s[16];
  __shared__ float lossr[16];

  const int t = threadIdx.x;
  const int w = t >> 6;  // wave 0..15
  const int lane = t & 63;
  const int lr = lane & 15, kg = lane >> 4;
  const int R = blockIdx.x * 16;  // this block's 16 rows

  if (t < 16) labrow_s[t] = labels[(R + t) & 1023];

  // A fragments: this block's 16-row group, coalesced, loaded once
  half8 af[6];
  {
    const _Float16* abase = cfnF + (size_t)blockIdx.x * 3072 + kg * 128 + lr * 8;
#pragma unroll
    for (int kc = 0; kc < 6; ++kc) af[kc] = *(const half8*)&abase[kc * 512];
  }

  // main loop: 8 col-groups of 16, all loads coalesced 16B/lane, no barriers
  f32x4 acc[8];
#pragma unroll
  for (int j = 0; j < 8; ++j) {
    const int g = w * 8 + j;  // col group: cols g*16 + lr
    const _Float16* bbase = cfnF + (size_t)g * 3072 + kg * 128 + lr * 8;
    half8 bf[6];
#pragma unroll
    for (int kc = 0; kc < 6; ++kc) bf[kc] = *(const half8*)&bbase[kc * 512];
    f32x4 a = (f32x4){0.f, 0.f, 0.f, 0.f};
#pragma unroll
    for (int kc = 0; kc < 6; ++kc)
      a = __builtin_amdgcn_mfma_f32_16x16x32_f16(af[kc], bf[kc], a, 0, 0, 0);
    acc[j] = a;  // C: row = R + kg*4+e, col = w*128 + j*16 + lr
  }

  // ---- row stats from f32 acc (pre-rounding; validated R12/R13) ----
  float ssv[4], mxv[4];
#pragma unroll
  for (int e = 0; e < 4; ++e) { ssv[e] = 0.f; mxv[e] = -3.4e38f; }
#pragma unroll
  for (int j = 0; j < 8; ++j)
#pragma unroll
    for (int e = 0; e < 4; ++e) {
      const float c = acc[j][e];
      ssv[e] += c * c;
      mxv[e] = fmaxf(mxv[e], c);
    }
#pragma unroll
  for (int o = 1; o < 16; o <<= 1)
#pragma unroll
    for (int e = 0; e < 4; ++e) {
      ssv[e] += __shfl_xor(ssv[e], o);
      mxv[e] = fmaxf(mxv[e], __shfl_xor(mxv[e], o));
    }
  if (lr == 0)
#pragma unroll
    for (int e = 0; e < 4; ++e) {
      sstat[0][kg * 4 + e][w] = ssv[e];
      sstat[1][kg * 4 + e][w] = mxv[e];
    }
  __syncthreads();

  float invn[4], Mst[4];
#pragma unroll
  for (int e = 0; e < 4; ++e) {
    float ss = 0.f, mx = -3.4e38f;
#pragma unroll
    for (int q = 0; q < 16; ++q) {
      ss += sstat[0][kg * 4 + e][q];
      mx = fmaxf(mx, sstat[1][kg * 4 + e][q]);
    }
    invn[e] = 1.0f / fmaxf(sqrtf(ss), 1e-12f);
    Mst[e] = xform(mx * invn[e]);  // stabilizer (loss-invariant choice)
  }

  // ---- exp pass straight from registers ----
  float es[4] = {0.f, 0.f, 0.f, 0.f}, ps[4] = {0.f, 0.f, 0.f, 0.f},
        cn[4] = {0.f, 0.f, 0.f, 0.f};
#pragma unroll
  for (int j = 0; j < 8; ++j) {
    const int col = w * 128 + j * 16 + lr;
    const int lcol = labels[col & 1023];  // 8KB table: L1-resident
#pragma unroll
    for (int e = 0; e < 4; ++e) {
      const int irow = R + kg * 4 + e;
      const float lg = xform(acc[j][e] * invn[e]) - Mst[e];
      if (col != irow) {
        es[e] += exp2f(lg * LOG2E);
        if (lcol == labrow_s[kg * 4 + e]) { ps[e] += lg; cn[e] += 1.f; }
      }
    }
  }
#pragma unroll
  for (int o = 1; o < 16; o <<= 1)
#pragma unroll
    for (int e = 0; e < 4; ++e) {
      es[e] += __shfl_xor(es[e], o);
      ps[e] += __shfl_xor(ps[e], o);
      cn[e] += __shfl_xor(cn[e], o);
    }
  if (lr == 0)
#pragma unroll
    for (int e = 0; e < 4; ++e) {
      estat[0][kg * 4 + e][w] = es[e];
      estat[1][kg * 4 + e][w] = ps[e];
      estat[2][kg * 4 + e][w] = cn[e];
    }
  __syncthreads();

  // ---- finish: 256 threads, row = t>>4, wave-slot q = t&15 ----
  if (t < 256) {
    const int row = t >> 4, q = t & 15;
    float e_ = estat[0][row][q], p_ = estat[1][row][q], c_ = estat[2][row][q];
#pragma unroll
    for (int o = 1; o < 16; o <<= 1) {  // masks 1,2,4,8: stay in 16-group
      e_ += __shfl_xor(e_, o);
      p_ += __shfl_xor(p_, o);
      c_ += __shfl_xor(c_, o);
    }
    if (q == 0) lossr[row] = -(p_ / c_ - log2f(e_) * LN2);
  }
  __syncthreads();
  if (t == 0) {
    float s = 0.f;
#pragma unroll
    for (int r = 0; r < 16; ++r) s += lossr[r];
    atomicAdd(out, s * (1.0f / 2048.0f));  // 128 atomics total
  }
}

extern "C" void kernel_launch(void* const* d_in, const int* in_sizes, int n_in,
                              void* d_out, int out_size, void* d_ws, size_t ws_size,
                              hipStream_t stream) {
  const float* feats = (const float*)d_in[0];
  const int* labels = (const int*)d_in[1];
  // d_in[2]/d_in[3] (fc_w/fc_b) are provably dead: atten == 1.0 exactly

  _Float16* cfnF = (_Float16*)d_ws;  // 2048*192*2 = 768 KiB, fragment-major

  k_normfrag<<<2048, 64, 0, stream>>>(feats, cfnF, (float*)d_out);
  k_fused<<<128, 1024, 0, stream>>>(cfnF, labels, (float*)d_out);
}

// Round 15
// 30.087 us; speedup vs baseline: 1.6603x; 1.3012x over previous
//
#include <hip/hip_runtime.h>

typedef __attribute__((ext_vector_type(8))) _Float16 half8;
typedef __attribute__((ext_vector_type(4))) float f32x4;

// ---- constants from the reference ----
#define COS_M 0.98006657784124163f
#define SIN_M 0.19866933079506122f
#define TH_C  (-0.98006657784124163f)
#define MM_C  0.039733866159012244f
#define S_OVER_TEMP (10.0f / 0.07f)
#define LOG2E 1.44269504088896340736f
#define LN2   0.69314718055994530942f

// monotone-in-c transform: c -> S*phi(c)/TEMP (loss invariant to stabilizer
// choice, so xform(rowmax * invn) works as the log-sum-exp stabilizer)
__device__ inline float xform(float c) {
  float s2 = fmaxf(1.0f - c * c, 0.0f);
  float sn = sqrtf(s2);
  float phi = c * COS_M - sn * SIN_M;
  float out = (c - TH_C > 0.0f) ? phi : (c - MM_C);
  return out * S_OVER_TEMP;
}

// ---- K2': fused normalize + G = norm(F)*norm(F)^T -> f16, 64x64 tiles ------
// R10's proven math (raw-f16 staging + rsA*rsB epilogue identity, R1-shape
// store) at 64-tile granularity: 1024 blocks, 51.2 KB LDS -> 3 blocks/CU,
// 3 waves/SIMD (vs R10's 1 block/CU, 2/SIMD) for latency hiding.
__global__ __launch_bounds__(256) void k_gemm_norm(const float* __restrict__ feats,
                                                   _Float16* __restrict__ Gh,
                                                   float* __restrict__ out) {
  __shared__ alignas(16) _Float16 la[64 * 200];  // stride 200: 2-way alias = free
  __shared__ alignas(16) _Float16 lb[64 * 200];
  __shared__ float rsA[64], rsBs[64];
  const int bm = blockIdx.x, bn = blockIdx.y;
  const int t = threadIdx.x;
  const bool diag = (bn == bm);
  if (bm == 0 && bn == 0 && t == 0) out[0] = 0.0f;  // stream-ordered before K3

  // stage one 64-row tile: 4 threads/row, 48 floats each; rowwise sumsq -> rs
  auto stage = [&](int bt, _Float16* lds, float* rs) {
    const int rr = t >> 2, h = t & 3;
    const int r = bt * 64 + rr;
    const float4* s4 =
        (const float4*)(feats + (size_t)((r & 1023) * 2 + (r >> 10)) * 192 + h * 48);
    float ss = 0.f;
    _Float16* dst = lds + rr * 200 + h * 48;
#pragma unroll
    for (int q = 0; q < 6; ++q) {
      float4 va = s4[2 * q], vb = s4[2 * q + 1];
      ss += va.x * va.x + va.y * va.y + va.z * va.z + va.w * va.w;
      ss += vb.x * vb.x + vb.y * vb.y + vb.z * vb.z + vb.w * vb.w;
      half8 o = {(_Float16)va.x, (_Float16)va.y, (_Float16)va.z, (_Float16)va.w,
                 (_Float16)vb.x, (_Float16)vb.y, (_Float16)vb.z, (_Float16)vb.w};
      *(half8*)(dst + q * 8) = o;
    }
    ss += __shfl_xor(ss, 1);  // 4-lane group = full row
    ss += __shfl_xor(ss, 2);
    if (h == 0) rs[rr] = rsqrtf(fmaxf(ss, 1e-24f));
  };
  stage(bm, la, rsA);
  if (!diag) stage(bn, lb, rsBs);
  __syncthreads();
  const _Float16* Bp = diag ? la : lb;
  const float* rsB = diag ? rsA : rsBs;

  const int lane = t & 63;
  const int w = t >> 6;               // 4 waves
  const int wr = w >> 1, wc = w & 1;  // 2x2 wave grid, 32x32 each
  const int lr = lane & 15, kg = lane >> 4;

  f32x4 acc[2][2];
#pragma unroll
  for (int m = 0; m < 2; ++m)
#pragma unroll
    for (int n = 0; n < 2; ++n) acc[m][n] = (f32x4){0.f, 0.f, 0.f, 0.f};

#pragma unroll
  for (int kc = 0; kc < 6; ++kc) {  // K = 192 = 6 * 32
    half8 af[2], bf[2];
    const int koff = kc * 32 + kg * 8;
#pragma unroll
    for (int m = 0; m < 2; ++m)
      af[m] = *(const half8*)&la[(wr * 32 + m * 16 + lr) * 200 + koff];
#pragma unroll
    for (int n = 0; n < 2; ++n)
      bf[n] = *(const half8*)&Bp[(wc * 32 + n * 16 + lr) * 200 + koff];
#pragma unroll
    for (int m = 0; m < 2; ++m)
#pragma unroll
      for (int n = 0; n < 2; ++n)
        acc[m][n] = __builtin_amdgcn_mfma_f32_16x16x32_f16(af[m], bf[n], acc[m][n], 0, 0, 0);
  }

  const int rb = bm * 64 + wr * 32;
  const int cb = bn * 64 + wc * 32;
#pragma unroll
  for (int m = 0; m < 2; ++m)
#pragma unroll
    for (int n = 0; n < 2; ++n) {
      const int r0 = rb + m * 16 + kg * 4;  // C/D: col=lane&15, row=(lane>>4)*4+e
      const int c0 = cb + n * 16 + lr;
      const float sb = rsB[wc * 32 + n * 16 + lr];
#pragma unroll
      for (int e = 0; e < 4; ++e) {  // R1-shape store (validated R4-R14)
        const float sa = rsA[wr * 32 + m * 16 + kg * 4 + e];
        Gh[(size_t)(r0 + e) * 2048 + c0] = (_Float16)(acc[m][n][e] * sa * sb);
      }
    }
}

// ---- K3: 4 independent waves/block, one row each (proven R7-R10 math), LDS
// tail gather + ONE atomicAdd per block (512 total). No fences, no spinning.
__global__ __launch_bounds__(256) void k_rowloss(const _Float16* __restrict__ Gh,
                                                 const int* __restrict__ labels,
                                                 float* __restrict__ out) {
  const int w = threadIdx.x >> 6;
  const int l = threadIdx.x & 63;
  const int i = blockIdx.x * 4 + w;  // this wave's row
  const _Float16* row = Gh + (size_t)i * 2048;

  half8 v[4];
#pragma unroll
  for (int p = 0; p < 4; ++p)  // 4 independent 16B loads in flight
    v[p] = *(const half8*)&row[512 * p + 8 * l];

  float gv[4][8];
#pragma unroll
  for (int p = 0; p < 4; ++p)
#pragma unroll
    for (int u = 0; u < 8; ++u) gv[p][u] = (float)v[p][u];

  float ss = 0.f, mx = -3.4e38f;
#pragma unroll
  for (int p = 0; p < 4; ++p)
#pragma unroll
    for (int u = 0; u < 8; ++u) { ss += gv[p][u] * gv[p][u]; mx = fmaxf(mx, gv[p][u]); }
#pragma unroll
  for (int o = 32; o; o >>= 1) {  // wave-wide butterfly, no LDS
    ss += __shfl_xor(ss, o);
    mx = fmaxf(mx, __shfl_xor(mx, o));
  }
  const float invn = 1.0f / fmaxf(sqrtf(ss), 1e-12f);
  const float Mst = xform(mx * invn);  // stabilizer (loss-invariant choice)

  const int4 a0 = *(const int4*)&labels[8 * l];
  const int4 a1 = *(const int4*)&labels[8 * l + 4];
  const int4 b0 = *(const int4*)&labels[512 + 8 * l];
  const int4 b1 = *(const int4*)&labels[512 + 8 * l + 4];
  const int labs[2][8] = {{a0.x, a0.y, a0.z, a0.w, a1.x, a1.y, a1.z, a1.w},
                          {b0.x, b0.y, b0.z, b0.w, b1.x, b1.y, b1.z, b1.w}};
  const int mylab = labels[i & 1023];  // wave-uniform -> scalar load

  float es = 0.f, ps = 0.f, cn = 0.f;
#pragma unroll
  for (int p = 0; p < 4; ++p)
#pragma unroll
    for (int u = 0; u < 8; ++u) {
      const int j = 512 * p + 8 * l + u;
      const float lg = xform(gv[p][u] * invn) - Mst;
      if (j != i) {
        es += exp2f(lg * LOG2E);  // exp(lg)
        if (labs[p & 1][u] == mylab) { ps += lg; cn += 1.f; }
      }
    }
#pragma unroll
  for (int o = 32; o; o >>= 1) {
    es += __shfl_xor(es, o);
    ps += __shfl_xor(ps, o);
    cn += __shfl_xor(cn, o);
  }

  __shared__ float part[4];
  if (l == 0) part[w] = -(ps / cn - log2f(es) * LN2);
  __syncthreads();
  if (threadIdx.x == 0)
    atomicAdd(out, (part[0] + part[1] + part[2] + part[3]) * (1.0f / 2048.0f));
}

extern "C" void kernel_launch(void* const* d_in, const int* in_sizes, int n_in,
                              void* d_out, int out_size, void* d_ws, size_t ws_size,
                              hipStream_t stream) {
  const float* feats = (const float*)d_in[0];
  const int* labels = (const int*)d_in[1];
  // d_in[2]/d_in[3] (fc_w/fc_b) are provably dead: atten == 1.0 exactly

  char* ws = (char*)d_ws;
  _Float16* Gh = (_Float16*)(ws + (1 << 20));  // 2048*2048*2 = 8 MiB

  dim3 g2(32, 32);
  k_gemm_norm<<<g2, 256, 0, stream>>>(feats, Gh, (float*)d_out);
  k_rowloss<<<512, 256, 0, stream>>>(Gh, labels, (float*)d_out);
}

// Round 16
// 27.866 us; speedup vs baseline: 1.7926x; 1.0797x over previous
//
#include <hip/hip_runtime.h>

typedef __attribute__((ext_vector_type(8))) _Float16 half8;
typedef __attribute__((ext_vector_type(4))) float f32x4;

// ---- constants from the reference ----
#define COS_M 0.98006657784124163f
#define SIN_M 0.19866933079506122f
#define TH_C  (-0.98006657784124163f)
#define MM_C  0.039733866159012244f
#define S_OVER_TEMP (10.0f / 0.07f)
#define LOG2E 1.44269504088896340736f
#define LN2   0.69314718055994530942f

// monotone-in-c transform: c -> S*phi(c)/TEMP (loss invariant to stabilizer
// choice, so xform(rowmax * invn) works as the log-sum-exp stabilizer)
__device__ inline float xform(float c) {
  float s2 = fmaxf(1.0f - c * c, 0.0f);
  float sn = sqrtf(s2);
  float phi = c * COS_M - sn * SIN_M;
  float out = (c - TH_C > 0.0f) ? phi : (c - MM_C);
  return out * S_OVER_TEMP;
}

// ---- K2': fused normalize + G = norm(F)*norm(F)^T -> f16, 8 waves/block ----
// (R10-proven best: 128x128 tile, 512 threads -> 2 waves/SIMD, raw-f16
// staging + rsA*rsB epilogue identity, R1-shape coalesced f16 store.)
__global__ __launch_bounds__(512) void k_gemm_norm(const float* __restrict__ feats,
                                                   _Float16* __restrict__ Gh,
                                                   float* __restrict__ out) {
  __shared__ alignas(16) _Float16 la[128 * 200];  // stride 200: 2-way alias = free
  __shared__ alignas(16) _Float16 lb[128 * 200];
  __shared__ float rsA[128], rsBs[128];
  const int bm = blockIdx.x, bn = blockIdx.y;
  const int t = threadIdx.x;
  const bool diag = (bn == bm);
  if (bm == 0 && bn == 0 && t == 0) out[0] = 0.0f;  // stream-ordered before K3

  // stage one 128-row tile: 4 threads/row, 48 floats each; rowwise sumsq -> rs
  auto stage = [&](int bt, _Float16* lds, float* rs) {
    const int rr = t >> 2, h = t & 3;
    const int r = bt * 128 + rr;
    const float4* s4 =
        (const float4*)(feats + (size_t)((r & 1023) * 2 + (r >> 10)) * 192 + h * 48);
    float ss = 0.f;
    _Float16* dst = lds + rr * 200 + h * 48;
#pragma unroll
    for (int q = 0; q < 6; ++q) {
      float4 va = s4[2 * q], vb = s4[2 * q + 1];
      ss += va.x * va.x + va.y * va.y + va.z * va.z + va.w * va.w;
      ss += vb.x * vb.x + vb.y * vb.y + vb.z * vb.z + vb.w * vb.w;
      half8 o = {(_Float16)va.x, (_Float16)va.y, (_Float16)va.z, (_Float16)va.w,
                 (_Float16)vb.x, (_Float16)vb.y, (_Float16)vb.z, (_Float16)vb.w};
      *(half8*)(dst + q * 8) = o;
    }
    ss += __shfl_xor(ss, 1);  // 4-lane group = full row
    ss += __shfl_xor(ss, 2);
    if (h == 0) rs[rr] = rsqrtf(fmaxf(ss, 1e-24f));
  };
  stage(bm, la, rsA);
  if (!diag) stage(bn, lb, rsBs);
  __syncthreads();
  const _Float16* Bp = diag ? la : lb;
  const float* rsB = diag ? rsA : rsBs;

  const int lane = t & 63;
  const int w = t >> 6;               // 8 waves
  const int wr = w >> 2, wc = w & 3;  // 2x4 wave grid, 64x32 each
  const int lr = lane & 15, kg = lane >> 4;

  f32x4 acc[4][2];
#pragma unroll
  for (int m = 0; m < 4; ++m)
#pragma unroll
    for (int n = 0; n < 2; ++n) acc[m][n] = (f32x4){0.f, 0.f, 0.f, 0.f};

#pragma unroll
  for (int kc = 0; kc < 6; ++kc) {  // K = 192 = 6 * 32
    half8 af[4], bf[2];
    const int koff = kc * 32 + kg * 8;
#pragma unroll
    for (int m = 0; m < 4; ++m)
      af[m] = *(const half8*)&la[(wr * 64 + m * 16 + lr) * 200 + koff];
#pragma unroll
    for (int n = 0; n < 2; ++n)
      bf[n] = *(const half8*)&Bp[(wc * 32 + n * 16 + lr) * 200 + koff];
#pragma unroll
    for (int m = 0; m < 4; ++m)
#pragma unroll
      for (int n = 0; n < 2; ++n)
        acc[m][n] = __builtin_amdgcn_mfma_f32_16x16x32_f16(af[m], bf[n], acc[m][n], 0, 0, 0);
  }

  const int rb = bm * 128 + wr * 64;
  const int cb = bn * 128 + wc * 32;
#pragma unroll
  for (int m = 0; m < 4; ++m)
#pragma unroll
    for (int n = 0; n < 2; ++n) {
      const int r0 = rb + m * 16 + kg * 4;  // C/D: col=lane&15, row=(lane>>4)*4+e
      const int c0 = cb + n * 16 + lr;
      const float sb = rsB[wc * 32 + n * 16 + lr];
#pragma unroll
      for (int e = 0; e < 4; ++e) {  // R1-shape store (validated R4-R15)
        const float sa = rsA[wr * 64 + m * 16 + kg * 4 + e];
        Gh[(size_t)(r0 + e) * 2048 + c0] = (_Float16)(acc[m][n][e] * sa * sb);
      }
    }
}

// ---- K3: 4 independent waves/block, one row each (proven R7-R10 math), LDS
// tail gather + ONE atomicAdd per block (512 total). No fences, no spinning.
__global__ __launch_bounds__(256) void k_rowloss(const _Float16* __restrict__ Gh,
                                                 const int* __restrict__ labels,
                                                 float* __restrict__ out) {
  const int w = threadIdx.x >> 6;
  const int l = threadIdx.x & 63;
  const int i = blockIdx.x * 4 + w;  // this wave's row
  const _Float16* row = Gh + (size_t)i * 2048;

  half8 v[4];
#pragma unroll
  for (int p = 0; p < 4; ++p)  // 4 independent 16B loads in flight
    v[p] = *(const half8*)&row[512 * p + 8 * l];

  float gv[4][8];
#pragma unroll
  for (int p = 0; p < 4; ++p)
#pragma unroll
    for (int u = 0; u < 8; ++u) gv[p][u] = (float)v[p][u];

  float ss = 0.f, mx = -3.4e38f;
#pragma unroll
  for (int p = 0; p < 4; ++p)
#pragma unroll
    for (int u = 0; u < 8; ++u) { ss += gv[p][u] * gv[p][u]; mx = fmaxf(mx, gv[p][u]); }
#pragma unroll
  for (int o = 32; o; o >>= 1) {  // wave-wide butterfly, no LDS
    ss += __shfl_xor(ss, o);
    mx = fmaxf(mx, __shfl_xor(mx, o));
  }
  const float invn = 1.0f / fmaxf(sqrtf(ss), 1e-12f);
  const float Mst = xform(mx * invn);  // stabilizer (loss-invariant choice)

  const int4 a0 = *(const int4*)&labels[8 * l];
  const int4 a1 = *(const int4*)&labels[8 * l + 4];
  const int4 b0 = *(const int4*)&labels[512 + 8 * l];
  const int4 b1 = *(const int4*)&labels[512 + 8 * l + 4];
  const int labs[2][8] = {{a0.x, a0.y, a0.z, a0.w, a1.x, a1.y, a1.z, a1.w},
                          {b0.x, b0.y, b0.z, b0.w, b1.x, b1.y, b1.z, b1.w}};
  const int mylab = labels[i & 1023];  // wave-uniform -> scalar load

  float es = 0.f, ps = 0.f, cn = 0.f;
#pragma unroll
  for (int p = 0; p < 4; ++p)
#pragma unroll
    for (int u = 0; u < 8; ++u) {
      const int j = 512 * p + 8 * l + u;
      const float lg = xform(gv[p][u] * invn) - Mst;
      if (j != i) {
        es += exp2f(lg * LOG2E);  // exp(lg)
        if (labs[p & 1][u] == mylab) { ps += lg; cn += 1.f; }
      }
    }
#pragma unroll
  for (int o = 32; o; o >>= 1) {
    es += __shfl_xor(es, o);
    ps += __shfl_xor(ps, o);
    cn += __shfl_xor(cn, o);
  }

  __shared__ float part[4];
  if (l == 0) part[w] = -(ps / cn - log2f(es) * LN2);
  __syncthreads();
  if (threadIdx.x == 0)
    atomicAdd(out, (part[0] + part[1] + part[2] + part[3]) * (1.0f / 2048.0f));
}

extern "C" void kernel_launch(void* const* d_in, const int* in_sizes, int n_in,
                              void* d_out, int out_size, void* d_ws, size_t ws_size,
                              hipStream_t stream) {
  const float* feats = (const float*)d_in[0];
  const int* labels = (const int*)d_in[1];
  // d_in[2]/d_in[3] (fc_w/fc_b) are provably dead: atten == 1.0 exactly

  char* ws = (char*)d_ws;
  _Float16* Gh = (_Float16*)(ws + (1 << 20));  // 2048*2048*2 = 8 MiB

  dim3 g2(16, 16);
  k_gemm_norm<<<g2, 512, 0, stream>>>(feats, Gh, (float*)d_out);
  k_rowloss<<<512, 256, 0, stream>>>(Gh, labels, (float*)d_out);
}